// Round 1
// baseline (1555.999 us; speedup 1.0000x reference)
//
#include <hip/hip_runtime.h>

// ---------------------------------------------------------------------------
// XposMultiheadAttention  (B=8, T=S=1024, E=1024, H=16, D=64, fp32)
// Baseline round: fp32 everywhere (matches reference numerics closely).
// Pipeline: xpos tables -> q/k/v projections (xpos fused in epilogue, output
// in (B,H,T,D)) -> flash attention (online softmax) -> output projection.
// ---------------------------------------------------------------------------

#define BSZ  8
#define SEQ  1024
#define EMB  1024
#define NH   16
#define HD   64
#define HALF 32            // HD/2
#define BH   (BSZ*NH)      // 128
#define MROWS (BSZ*SEQ)    // 8192

// ---------------------------------------------------------------------------
// Kernel 1: xPos sin/cos tables.
// tab layout: [0]=sin*scale (q), [1]=cos*scale (q), [2]=sin/scale (k),
//             [3]=cos/scale (k); each SEQ*HALF floats.
// ---------------------------------------------------------------------------
__global__ __launch_bounds__(256)
void xpos_tables_kernel(float* __restrict__ tab) {
    int idx = blockIdx.x * 256 + threadIdx.x;      // SEQ*HALF = 32768
    if (idx >= SEQ * HALF) return;
    int t = idx >> 5;                              // position
    int j = idx & 31;                              // pair index
    float s        = (2.0f * (float)j + 0.4f * (float)HD) / (1.4f * (float)HD);
    float pos      = (float)(t - SEQ / 2);
    float scale    = powf(s, pos * (1.0f / 1024.0f));     // SCALE_BASE = 1024
    float inv_freq = powf(10000.0f, -(float)j / (float)HALF);
    float ang      = (float)t * inv_freq;
    float sn = sinf(ang), cs = cosf(ang);
    float inv_scale = 1.0f / scale;
    tab[0 * SEQ * HALF + idx] = sn * scale;
    tab[1 * SEQ * HALF + idx] = cs * scale;
    tab[2 * SEQ * HALF + idx] = sn * inv_scale;
    tab[3 * SEQ * HALF + idx] = cs * inv_scale;
}

// ---------------------------------------------------------------------------
// Kernel 2: projection GEMM  Y[m,n] = sum_k X[m,k]*W[n,k] + bias[n]
// MODE 0 = v (bias only), 1 = q (bias, *0.125, xpos upscale),
// 2 = k (bias, xpos downscale).
// Output layout (B,H,T,D); block tile 64x64, BK=16, 256 threads, 4x4 micro.
// LDS rows padded to 68 floats: stores 2-way max, compute reads conflict-free.
// ---------------------------------------------------------------------------
template <int MODE>
__global__ __launch_bounds__(256)
void proj_qkv_kernel(const float* __restrict__ X, const float* __restrict__ W,
                     const float* __restrict__ bias, const float* __restrict__ tab,
                     float* __restrict__ out) {
    __shared__ float As[16][68];
    __shared__ float Bs[16][68];
    const int tid  = threadIdx.x;
    const int tx   = tid & 15, ty = tid >> 4;
    const int row0 = blockIdx.x * 64;          // rows = b*SEQ + t
    const int h    = blockIdx.y;               // head = output col block
    const int col0 = h * 64;
    const int mm   = tid >> 2;                 // 0..63 (tile row for loads)
    const int k4   = (tid & 3) * 4;            // 0,4,8,12 (k offset for loads)

    float c[4][4] = {{0.f}};

    for (int k0 = 0; k0 < EMB; k0 += 16) {
        float4 a4 = *reinterpret_cast<const float4*>(
            &X[(size_t)(row0 + mm) * EMB + k0 + k4]);
        float4 b4 = *reinterpret_cast<const float4*>(
            &W[(size_t)(col0 + mm) * EMB + k0 + k4]);
        As[k4 + 0][mm] = a4.x; As[k4 + 1][mm] = a4.y;
        As[k4 + 2][mm] = a4.z; As[k4 + 3][mm] = a4.w;
        Bs[k4 + 0][mm] = b4.x; Bs[k4 + 1][mm] = b4.y;
        Bs[k4 + 2][mm] = b4.z; Bs[k4 + 3][mm] = b4.w;
        __syncthreads();
        #pragma unroll
        for (int kk = 0; kk < 16; ++kk) {
            float a_[4], b_[4];
            *reinterpret_cast<float4*>(a_) =
                *reinterpret_cast<const float4*>(&As[kk][ty * 4]);
            *reinterpret_cast<float4*>(b_) =
                *reinterpret_cast<const float4*>(&Bs[kk][tx * 4]);
            #pragma unroll
            for (int i = 0; i < 4; ++i)
                #pragma unroll
                for (int j = 0; j < 4; ++j)
                    c[i][j] = fmaf(a_[i], b_[j], c[i][j]);
        }
        __syncthreads();
    }

    // Epilogue: bias (+ scale) (+ xpos rotation), write (B,H,T,D).
    float bj[4];
    *reinterpret_cast<float4*>(bj) =
        *reinterpret_cast<const float4*>(&bias[col0 + tx * 4]);
    #pragma unroll
    for (int i = 0; i < 4; ++i) {
        int row = row0 + ty * 4 + i;
        int t   = row & (SEQ - 1);
        int b   = row >> 10;
        float vals[4];
        #pragma unroll
        for (int j = 0; j < 4; ++j) {
            vals[j] = c[i][j] + bj[j];
            if (MODE == 1) vals[j] *= 0.125f;      // HEAD_DIM^-0.5
        }
        if (MODE != 0) {
            const int base = (MODE == 1 ? 0 : 2) * SEQ * HALF + t * HALF;
            #pragma unroll
            for (int pp = 0; pp < 2; ++pp) {
                int   pidx = tx * 2 + pp;          // pair index within head
                float sn = tab[base + pidx];
                float cs = tab[base + SEQ * HALF + pidx];
                float x1 = vals[2 * pp], x2 = vals[2 * pp + 1];
                vals[2 * pp]     = x1 * cs - x2 * sn;
                vals[2 * pp + 1] = x2 * cs + x1 * sn;
            }
        }
        float4 o4 = make_float4(vals[0], vals[1], vals[2], vals[3]);
        *reinterpret_cast<float4*>(
            &out[(((size_t)b * NH + h) * SEQ + t) * HD + tx * 4]) = o4;
    }
}

// ---------------------------------------------------------------------------
// Kernel 3: flash attention (fp32). One block = 64 q-rows of one (b,h).
// Online softmax; P reuses K's LDS (scores fully in regs before overwrite).
// Score cols mapped c = tx + 16*j so K-row LDS reads are stride-68*1 per
// lane -> 2-way (free). Output overwrites the q buffer (q consumed first).
// ---------------------------------------------------------------------------
__global__ __launch_bounds__(256)
void attn_kernel(float* qo, const float* __restrict__ kg,
                 const float* __restrict__ vg) {
    __shared__ float Qs[64][68];
    __shared__ float Ks[64][68];
    __shared__ float Vs[64][68];
    float (*Ps)[68] = Ks;                      // P overlays K

    const int tid = threadIdx.x;
    const int tx  = tid & 15, ty = tid >> 4;
    const int bh  = blockIdx.y;
    const int q0  = blockIdx.x * 64;
    float*       qb = qo + (size_t)bh * SEQ * HD + (size_t)q0 * HD;
    const float* kb = kg + (size_t)bh * SEQ * HD;
    const float* vb = vg + (size_t)bh * SEQ * HD;

    // Load Q tile (64x64) into LDS.
    #pragma unroll
    for (int l = 0; l < 4; ++l) {
        int idx4 = tid + l * 256;
        int r = idx4 >> 4, d4c = (idx4 & 15) * 4;
        *reinterpret_cast<float4*>(&Qs[r][d4c]) =
            *reinterpret_cast<const float4*>(&qb[r * HD + d4c]);
    }
    float m_i[4], l_i[4], acc[4][4];
    #pragma unroll
    for (int i = 0; i < 4; ++i) {
        m_i[i] = -INFINITY; l_i[i] = 0.f;
        #pragma unroll
        for (int j = 0; j < 4; ++j) acc[i][j] = 0.f;
    }
    __syncthreads();

    for (int kt = 0; kt < SEQ; kt += 64) {
        // Load K,V tiles.
        #pragma unroll
        for (int l = 0; l < 4; ++l) {
            int idx4 = tid + l * 256;
            int r = idx4 >> 4, d4c = (idx4 & 15) * 4;
            *reinterpret_cast<float4*>(&Ks[r][d4c]) =
                *reinterpret_cast<const float4*>(&kb[(kt + r) * HD + d4c]);
            *reinterpret_cast<float4*>(&Vs[r][d4c]) =
                *reinterpret_cast<const float4*>(&vb[(kt + r) * HD + d4c]);
        }
        __syncthreads();

        // Scores: rows 4*ty+i, cols tx+16*j. (q pre-scaled by 0.125)
        float s[4][4] = {{0.f}};
        #pragma unroll
        for (int dstep = 0; dstep < 16; ++dstep) {
            float q_[4][4], k_[4][4];
            #pragma unroll
            for (int i = 0; i < 4; ++i)
                *reinterpret_cast<float4*>(q_[i]) =
                    *reinterpret_cast<const float4*>(&Qs[4 * ty + i][4 * dstep]);
            #pragma unroll
            for (int j = 0; j < 4; ++j)
                *reinterpret_cast<float4*>(k_[j]) =
                    *reinterpret_cast<const float4*>(&Ks[tx + 16 * j][4 * dstep]);
            #pragma unroll
            for (int i = 0; i < 4; ++i)
                #pragma unroll
                for (int j = 0; j < 4; ++j)
                    #pragma unroll
                    for (int dd = 0; dd < 4; ++dd)
                        s[i][j] = fmaf(q_[i][dd], k_[j][dd], s[i][j]);
        }

        // Online softmax (registers + shfl only; row group = 16 lanes).
        float alpha_[4];
        #pragma unroll
        for (int i = 0; i < 4; ++i) {
            float mx = fmaxf(fmaxf(s[i][0], s[i][1]), fmaxf(s[i][2], s[i][3]));
            mx = fmaxf(mx, __shfl_xor(mx, 1));
            mx = fmaxf(mx, __shfl_xor(mx, 2));
            mx = fmaxf(mx, __shfl_xor(mx, 4));
            mx = fmaxf(mx, __shfl_xor(mx, 8));
            float mnew = fmaxf(m_i[i], mx);
            alpha_[i]  = expf(m_i[i] - mnew);
            float rs = 0.f;
            #pragma unroll
            for (int j = 0; j < 4; ++j) {
                s[i][j] = expf(s[i][j] - mnew);
                rs += s[i][j];
            }
            rs += __shfl_xor(rs, 1);
            rs += __shfl_xor(rs, 2);
            rs += __shfl_xor(rs, 4);
            rs += __shfl_xor(rs, 8);
            l_i[i] = l_i[i] * alpha_[i] + rs;
            m_i[i] = mnew;
        }
        __syncthreads();                     // everyone done reading Ks
        #pragma unroll
        for (int i = 0; i < 4; ++i) {
            #pragma unroll
            for (int j = 0; j < 4; ++j) {
                Ps[4 * ty + i][tx + 16 * j] = s[i][j];
                acc[i][j] *= alpha_[i];
            }
        }
        __syncthreads();                     // P visible

        // PV: acc[i][j] += sum_c P[4ty+i][c] * V[c][4tx+j]
        #pragma unroll
        for (int cstep = 0; cstep < 16; ++cstep) {
            float p_[4][4], v_[4][4];
            #pragma unroll
            for (int i = 0; i < 4; ++i)
                *reinterpret_cast<float4*>(p_[i]) =
                    *reinterpret_cast<const float4*>(&Ps[4 * ty + i][4 * cstep]);
            #pragma unroll
            for (int cc = 0; cc < 4; ++cc)
                *reinterpret_cast<float4*>(v_[cc]) =
                    *reinterpret_cast<const float4*>(&Vs[4 * cstep + cc][4 * tx]);
            #pragma unroll
            for (int i = 0; i < 4; ++i)
                #pragma unroll
                for (int j = 0; j < 4; ++j)
                    #pragma unroll
                    for (int cc = 0; cc < 4; ++cc)
                        acc[i][j] = fmaf(p_[i][cc], v_[cc][j], acc[i][j]);
        }
        __syncthreads();                     // done with Ks/Ps/Vs this tile
    }

    // Epilogue: normalize and write back over the q buffer.
    #pragma unroll
    for (int i = 0; i < 4; ++i) {
        float inv = 1.0f / l_i[i];
        float4 o4 = make_float4(acc[i][0] * inv, acc[i][1] * inv,
                                acc[i][2] * inv, acc[i][3] * inv);
        *reinterpret_cast<float4*>(&qb[(4 * ty + i) * HD + 4 * tx]) = o4;
    }
}

// ---------------------------------------------------------------------------
// Kernel 4: output projection. A gathered from (B,H,T,D); out (B,T,E)+bias.
// ---------------------------------------------------------------------------
__global__ __launch_bounds__(256)
void proj_out_kernel(const float* __restrict__ A, const float* __restrict__ W,
                     const float* __restrict__ bias, float* __restrict__ out) {
    __shared__ float As[16][68];
    __shared__ float Bs[16][68];
    const int tid  = threadIdx.x;
    const int tx   = tid & 15, ty = tid >> 4;
    const int row0 = blockIdx.x * 64;
    const int col0 = blockIdx.y * 64;
    const int b    = row0 >> 10;                // 64 | SEQ so b const per block
    const int t0   = row0 & (SEQ - 1);
    const int mm   = tid >> 2;
    const int k4   = (tid & 3) * 4;

    float c[4][4] = {{0.f}};

    for (int k0 = 0; k0 < EMB; k0 += 16) {
        int h  = k0 >> 6;                       // 16 | 64 so h const per k-tile
        int d0 = k0 & 63;
        float4 a4 = *reinterpret_cast<const float4*>(
            &A[(((size_t)b * NH + h) * SEQ + t0 + mm) * HD + d0 + k4]);
        float4 b4 = *reinterpret_cast<const float4*>(
            &W[(size_t)(col0 + mm) * EMB + k0 + k4]);
        As[k4 + 0][mm] = a4.x; As[k4 + 1][mm] = a4.y;
        As[k4 + 2][mm] = a4.z; As[k4 + 3][mm] = a4.w;
        Bs[k4 + 0][mm] = b4.x; Bs[k4 + 1][mm] = b4.y;
        Bs[k4 + 2][mm] = b4.z; Bs[k4 + 3][mm] = b4.w;
        __syncthreads();
        #pragma unroll
        for (int kk = 0; kk < 16; ++kk) {
            float a_[4], b_[4];
            *reinterpret_cast<float4*>(a_) =
                *reinterpret_cast<const float4*>(&As[kk][ty * 4]);
            *reinterpret_cast<float4*>(b_) =
                *reinterpret_cast<const float4*>(&Bs[kk][tx * 4]);
            #pragma unroll
            for (int i = 0; i < 4; ++i)
                #pragma unroll
                for (int j = 0; j < 4; ++j)
                    c[i][j] = fmaf(a_[i], b_[j], c[i][j]);
        }
        __syncthreads();
    }

    float bj[4];
    *reinterpret_cast<float4*>(bj) =
        *reinterpret_cast<const float4*>(&bias[col0 + tx * 4]);
    #pragma unroll
    for (int i = 0; i < 4; ++i) {
        int row = row0 + ty * 4 + i;
        float4 o4 = make_float4(c[i][0] + bj[0], c[i][1] + bj[1],
                                c[i][2] + bj[2], c[i][3] + bj[3]);
        *reinterpret_cast<float4*>(&out[(size_t)row * EMB + col0 + tx * 4]) = o4;
    }
}

// ---------------------------------------------------------------------------
// Launch. ws layout (floats): q[8.4M] (also attn out) | k[8.4M] | v[8.4M] |
// tables[128K]  => ~101.2 MB total.
// ---------------------------------------------------------------------------
extern "C" void kernel_launch(void* const* d_in, const int* in_sizes, int n_in,
                              void* d_out, int out_size, void* d_ws,
                              size_t ws_size, hipStream_t stream) {
    const float* query = (const float*)d_in[0];
    const float* key_  = (const float*)d_in[1];
    const float* value = (const float*)d_in[2];
    const float* wq    = (const float*)d_in[3];
    const float* bq    = (const float*)d_in[4];
    const float* wk    = (const float*)d_in[5];
    const float* bk    = (const float*)d_in[6];
    const float* wv    = (const float*)d_in[7];
    const float* bv    = (const float*)d_in[8];
    const float* wo    = (const float*)d_in[9];
    const float* bo    = (const float*)d_in[10];
    float*       out   = (float*)d_out;
    float*       ws    = (float*)d_ws;

    const size_t QKV = (size_t)BH * SEQ * HD;   // 8388608
    float* qbuf = ws;
    float* kbuf = ws + QKV;
    float* vbuf = ws + 2 * QKV;
    float* tab  = ws + 3 * QKV;

    xpos_tables_kernel<<<dim3(SEQ * HALF / 256), 256, 0, stream>>>(tab);

    dim3 pgrid(MROWS / 64, NH);
    proj_qkv_kernel<1><<<pgrid, 256, 0, stream>>>(query, wq, bq, tab, qbuf);
    proj_qkv_kernel<2><<<pgrid, 256, 0, stream>>>(key_,  wk, bk, tab, kbuf);
    proj_qkv_kernel<0><<<pgrid, 256, 0, stream>>>(value, wv, bv, tab, vbuf);

    attn_kernel<<<dim3(SEQ / 64, BH), 256, 0, stream>>>(qbuf, kbuf, vbuf);

    proj_out_kernel<<<dim3(MROWS / 64, NH), 256, 0, stream>>>(qbuf, wo, bo, out);
}

// Round 3
// 391.497 us; speedup vs baseline: 3.9745x; 3.9745x over previous
//
#include <hip/hip_runtime.h>

// ---------------------------------------------------------------------------
// XposMultiheadAttention (B=8, T=S=1024, E=1024, H=16, D=64) — bf16 MFMA
// cast fp32->bf16 (shared tmp) -> xpos tables -> 3x proj GEMM (MFMA, fused
// bias/scale/xpos, out (B,H,T,D) bf16) -> V transpose -> flash attn (MFMA,
// online softmax, double-buffered LDS) -> out proj (MFMA, fp32 out).
// ws budget: 76 MB (round-1 fp32 version proved >=101.2 MB available).
// ---------------------------------------------------------------------------

#define BSZ  8
#define SEQ  1024
#define EMB  1024
#define NH   16
#define HD   64
#define HALF 32
#define BH   (BSZ*NH)
#define MROWS (BSZ*SEQ)

typedef __attribute__((ext_vector_type(4))) float f32x4;
typedef __attribute__((ext_vector_type(8))) short bf16x8;

__device__ __forceinline__ ushort f2bf(float f) {
    union { float f; unsigned u; } v; v.f = f;
    return (ushort)((v.u + 0x7FFFu + ((v.u >> 16) & 1u)) >> 16);
}

// async global->LDS, 16B per lane; lds ptr must be the wave-uniform base.
__device__ __forceinline__ void async16(void* lds, const void* g) {
    __builtin_amdgcn_global_load_lds(
        (const __attribute__((address_space(1))) unsigned int*)g,
        (__attribute__((address_space(3))) unsigned int*)lds, 16, 0, 0);
}

// ---------------------------------------------------------------------------
// fp32 -> bf16 cast (vectorized)
// ---------------------------------------------------------------------------
__global__ __launch_bounds__(256)
void cast_kernel(const float* __restrict__ src, ushort* __restrict__ dst, int n4) {
    int i = blockIdx.x * 256 + threadIdx.x;
    if (i >= n4) return;
    float4 v = reinterpret_cast<const float4*>(src)[i];
    ushort4 o;
    o.x = f2bf(v.x); o.y = f2bf(v.y); o.z = f2bf(v.z); o.w = f2bf(v.w);
    reinterpret_cast<ushort4*>(dst)[i] = o;
}

// ---------------------------------------------------------------------------
// xPos tables: [0]=sin*scale (q), [1]=cos*scale (q), [2]=sin/scale (k),
// [3]=cos/scale (k); each SEQ*HALF floats.
// ---------------------------------------------------------------------------
__global__ __launch_bounds__(256)
void xpos_tables_kernel(float* __restrict__ tab) {
    int idx = blockIdx.x * 256 + threadIdx.x;
    if (idx >= SEQ * HALF) return;
    int t = idx >> 5;
    int j = idx & 31;
    float s        = (2.0f * (float)j + 0.4f * (float)HD) / (1.4f * (float)HD);
    float pos      = (float)(t - SEQ / 2);
    float scale    = powf(s, pos * (1.0f / 1024.0f));
    float inv_freq = powf(10000.0f, -(float)j / (float)HALF);
    float ang      = (float)t * inv_freq;
    float sn = sinf(ang), cs = cosf(ang);
    float inv_scale = 1.0f / scale;
    tab[0 * SEQ * HALF + idx] = sn * scale;
    tab[1 * SEQ * HALF + idx] = cs * scale;
    tab[2 * SEQ * HALF + idx] = sn * inv_scale;
    tab[3 * SEQ * HALF + idx] = cs * inv_scale;
}

// ---------------------------------------------------------------------------
// bf16 MFMA GEMM: Y[m,n] = sum_k A[m,k]*W[n,k] (+bias, +epilogue)
// 128x128 tile, BK=64, 256 thr (4 waves 2x2, each 64x64 = 4x4 frags 16x16x32).
// LDS tiles: linear [128 rows][128 bytes]; element at byte (r*128+cb) is
// global column ((cb ^ ((r&7)<<4))/2)  -> staged via pre-swizzled global src
// (global_load_lds writes linearly), read back with the same XOR (rule 21).
// MODE: 0=v(bias), 1=q(bias,*0.125,xpos up), 2=k(bias,xpos down) -> bf16
// (B,H,T,D);   3=out-proj (A gathered from (B,H,T,D)) -> f32 (B,T,E).
// ---------------------------------------------------------------------------
template <int MODE>
__global__ __launch_bounds__(256)
void gemm_bf16_kernel(const ushort* __restrict__ A, const ushort* __restrict__ W,
                      const float* __restrict__ bias, const float* __restrict__ tab,
                      void* __restrict__ outp) {
    __shared__ ushort As[128 * 64];
    __shared__ ushort Bs[128 * 64];
    const int tid  = threadIdx.x;
    const int lane = tid & 63;
    const int w    = tid >> 6;
    const int g    = lane >> 4;
    const int c    = lane & 15;
    const int wr   = w >> 1, wc = w & 1;

    // XCD-contiguous remap (512 blocks, 8 XCDs): each XCD gets 8 m-blocks x
    // all 8 n-blocks (A panel 2MB + W 2MB fits the 4MB per-XCD L2).
    int lid = blockIdx.x;
    int wg  = (lid & 7) * 64 + (lid >> 3);
    const int row0 = (wg >> 3) * 128;   // 64 m-blocks
    const int col0 = (wg & 7) * 128;    // 8 n-blocks

    f32x4 acc[4][4] = {};

    int srow[4], scol[4];
    #pragma unroll
    for (int i = 0; i < 4; ++i) {
        int f = i * 4096 + tid * 16;          // byte offset in LDS tile
        int r = f >> 7, cb = f & 127;
        srow[i] = r;
        scol[i] = (cb ^ ((r & 7) << 4)) >> 1; // element idx, pre-swizzled
    }

    for (int k0 = 0; k0 < EMB; k0 += 64) {
        #pragma unroll
        for (int i = 0; i < 4; ++i) {
            const ushort* srcA;
            if (MODE == 3) {
                int h = k0 >> 6;              // BK=64 == exactly one head
                srcA = &A[(((size_t)(row0 >> 10) * NH + h) * SEQ +
                           (row0 & 1023) + srow[i]) * HD + scol[i]];
            } else {
                srcA = &A[(size_t)(row0 + srow[i]) * EMB + k0 + scol[i]];
            }
            async16(&As[i * 2048 + w * 512], srcA);
        }
        #pragma unroll
        for (int i = 0; i < 4; ++i) {
            const ushort* srcB = &W[(size_t)(col0 + srow[i]) * EMB + k0 + scol[i]];
            async16(&Bs[i * 2048 + w * 512], srcB);
        }
        __syncthreads();   // compiler drains vmcnt before barrier

        #pragma unroll
        for (int ks = 0; ks < 2; ++ks) {
            bf16x8 af[4], bfr[4];
            #pragma unroll
            for (int mi = 0; mi < 4; ++mi) {
                int r = wr * 64 + mi * 16 + c;
                int byt = r * 128 + ((ks * 64 + g * 16) ^ ((r & 7) << 4));
                af[mi] = *reinterpret_cast<const bf16x8*>(
                    reinterpret_cast<const char*>(As) + byt);
            }
            #pragma unroll
            for (int ni = 0; ni < 4; ++ni) {
                int r = wc * 64 + ni * 16 + c;
                int byt = r * 128 + ((ks * 64 + g * 16) ^ ((r & 7) << 4));
                bfr[ni] = *reinterpret_cast<const bf16x8*>(
                    reinterpret_cast<const char*>(Bs) + byt);
            }
            #pragma unroll
            for (int mi = 0; mi < 4; ++mi)
                #pragma unroll
                for (int ni = 0; ni < 4; ++ni)
                    acc[mi][ni] = __builtin_amdgcn_mfma_f32_16x16x32_bf16(
                        af[mi], bfr[ni], acc[mi][ni], 0, 0, 0);
        }
        __syncthreads();
    }

    // Epilogue. C map (m89): col n = col0+wc*64+ni*16+c, row m = ...+g*4+r.
    #pragma unroll
    for (int ni = 0; ni < 4; ++ni) {
        int n = col0 + wc * 64 + ni * 16 + c;
        float bn = bias[n];
        #pragma unroll
        for (int mi = 0; mi < 4; ++mi) {
            #pragma unroll
            for (int r = 0; r < 4; ++r) {
                int m = row0 + wr * 64 + mi * 16 + g * 4 + r;
                float val = acc[mi][ni][r] + bn;
                if (MODE == 1) val *= 0.125f;          // HEAD_DIM^-0.5
                if (MODE == 1 || MODE == 2) {
                    int t = m & (SEQ - 1);
                    int d = n & 63;
                    const int base = (MODE == 1 ? 0 : 2) * SEQ * HALF + t * HALF;
                    float sn = tab[base + (d >> 1)];
                    float cs = tab[base + SEQ * HALF + (d >> 1)];
                    float other = __shfl_xor(val, 1);  // rotation partner d^1
                    val = val * cs + ((d & 1) ? other * sn : -other * sn);
                }
                if (MODE == 3) {
                    ((float*)outp)[(size_t)m * EMB + n] = val;
                } else {
                    int b = m >> 10, t = m & 1023;
                    int h = n >> 6,  d = n & 63;
                    ((ushort*)outp)[(((size_t)b * NH + h) * SEQ + t) * HD + d] =
                        f2bf(val);
                }
            }
        }
    }
}

// ---------------------------------------------------------------------------
// V transpose: (B,H,T,D) bf16 -> (B,H,D,T) bf16, 64x64 tiles.
// LDS rows padded to 72 ushorts (144B = 9x16B, keeps uint4 reads aligned).
// ---------------------------------------------------------------------------
__global__ __launch_bounds__(256)
void vtrans_kernel(const ushort* __restrict__ v, ushort* __restrict__ vt) {
    __shared__ ushort T[64][72];
    const int tid = threadIdx.x;
    const int bh  = blockIdx.y;
    const int t0  = blockIdx.x * 64;
    const ushort* vb = &v[((size_t)bh * SEQ + t0) * HD];
    #pragma unroll
    for (int p = 0; p < 2; ++p) {
        int chunk = p * 256 + tid;
        int tl = chunk >> 3;
        int d8 = (chunk & 7) * 8;
        ushort tmp[8];
        *reinterpret_cast<uint4*>(tmp) =
            *reinterpret_cast<const uint4*>(&vb[tl * HD + d8]);
        #pragma unroll
        for (int j = 0; j < 8; ++j) T[d8 + j][tl] = tmp[j];
    }
    __syncthreads();
    ushort* ob = &vt[(size_t)bh * HD * SEQ + t0];
    #pragma unroll
    for (int p = 0; p < 2; ++p) {
        int chunk = p * 256 + tid;
        int dl = chunk >> 3;
        int t8 = (chunk & 7) * 8;
        *reinterpret_cast<uint4*>(&ob[(size_t)dl * SEQ + t8]) =
            *reinterpret_cast<const uint4*>(&T[dl][t8]);
    }
}

// ---------------------------------------------------------------------------
// Flash attention, bf16 MFMA. Block = 64 q-rows of one (b,h); 4 waves, each
// owns 16 q-rows. Q in regs; K [key][d] and V^T [d][key] 64x64 tiles in LDS,
// double-buffered (prefetch next tile before compute, one barrier per tile);
// all tiles XOR-swizzled. P staged per-wave in swizzled LDS for the PV MFMA.
// ---------------------------------------------------------------------------
__global__ __launch_bounds__(256)
void attn_kernel(const ushort* __restrict__ qg, const ushort* __restrict__ kg,
                 const ushort* __restrict__ vtg, ushort* __restrict__ og) {
    __shared__ ushort Ks[2 * 4096];
    __shared__ ushort Vs[2 * 4096];
    __shared__ ushort Ps[4096];
    const int tid  = threadIdx.x;
    const int lane = tid & 63;
    const int w    = tid >> 6;
    const int g    = lane >> 4;
    const int c    = lane & 15;

    int lid = blockIdx.x;                     // 2048 blocks
    int wg  = (lid & 7) * 256 + (lid >> 3);   // XCD-contiguous, bh-major
    const int bh = wg >> 4;
    const int q0 = (wg & 15) * 64;

    // Q fragments held in registers (wave w owns q rows [w*16, w*16+16)).
    const ushort* qrow = &qg[((size_t)bh * SEQ + q0 + w * 16 + c) * HD];
    bf16x8 qf[2];
    qf[0] = *reinterpret_cast<const bf16x8*>(qrow + g * 8);
    qf[1] = *reinterpret_cast<const bf16x8*>(qrow + 32 + g * 8);

    float m_i[4], l_i[4];
    f32x4 oacc[4] = {};
    #pragma unroll
    for (int r = 0; r < 4; ++r) { m_i[r] = -1e30f; l_i[r] = 0.f; }

    int srow[2], scol[2];
    #pragma unroll
    for (int i = 0; i < 2; ++i) {
        int f = i * 4096 + tid * 16;
        int r = f >> 7, cb = f & 127;
        srow[i] = r; scol[i] = (cb ^ ((r & 7) << 4)) >> 1;
    }

    const ushort* kb  = &kg[(size_t)bh * SEQ * HD];
    const ushort* vtb = &vtg[(size_t)bh * HD * SEQ];

    auto stage = [&](int buf, int kt) {
        #pragma unroll
        for (int i = 0; i < 2; ++i) {
            async16(&Ks[buf * 4096 + i * 2048 + w * 512],
                    &kb[(size_t)(kt + srow[i]) * HD + scol[i]]);
            async16(&Vs[buf * 4096 + i * 2048 + w * 512],
                    &vtb[(size_t)srow[i] * SEQ + kt + scol[i]]);
        }
    };

    stage(0, 0);
    __syncthreads();

    char* pbase = reinterpret_cast<char*>(Ps) + w * 2048;

    for (int kt = 0; kt < SEQ; kt += 64) {
        const int cur = (kt >> 6) & 1;
        if (kt + 64 < SEQ) stage(cur ^ 1, kt + 64);  // prefetch overlaps compute

        const char* kbase = reinterpret_cast<const char*>(Ks) + cur * 8192;
        const char* vbase = reinterpret_cast<const char*>(Vs) + cur * 8192;

        // Scores: S[q=g*4+r][key=j*16+c]
        f32x4 s[4];
        #pragma unroll
        for (int j = 0; j < 4; ++j) {
            int key = j * 16 + c;
            int sw  = (key & 7) << 4;
            f32x4 a = {};
            #pragma unroll
            for (int ks = 0; ks < 2; ++ks) {
                bf16x8 kf = *reinterpret_cast<const bf16x8*>(
                    kbase + key * 128 + ((ks * 64 + g * 16) ^ sw));
                a = __builtin_amdgcn_mfma_f32_16x16x32_bf16(qf[ks], kf, a, 0, 0, 0);
            }
            s[j] = a;
        }

        // Online softmax (all 64 lanes active; row group = 16 lanes).
        float alpha[4];
        #pragma unroll
        for (int r = 0; r < 4; ++r) {
            float mx = fmaxf(fmaxf(s[0][r], s[1][r]), fmaxf(s[2][r], s[3][r]));
            mx = fmaxf(mx, __shfl_xor(mx, 1));
            mx = fmaxf(mx, __shfl_xor(mx, 2));
            mx = fmaxf(mx, __shfl_xor(mx, 4));
            mx = fmaxf(mx, __shfl_xor(mx, 8));
            float mn = fmaxf(m_i[r], mx);
            alpha[r] = __expf(m_i[r] - mn);
            float rs = 0.f;
            #pragma unroll
            for (int j = 0; j < 4; ++j) {
                float p = __expf(s[j][r] - mn);
                s[j][r] = p;
                rs += p;
            }
            rs += __shfl_xor(rs, 1);
            rs += __shfl_xor(rs, 2);
            rs += __shfl_xor(rs, 4);
            rs += __shfl_xor(rs, 8);
            l_i[r] = l_i[r] * alpha[r] + rs;
            m_i[r] = mn;
        }

        // Stage P (bf16) into per-wave swizzled LDS [16 rows][128 bytes].
        #pragma unroll
        for (int r = 0; r < 4; ++r) {
            int q  = g * 4 + r;
            int sw = (q & 7) << 4;
            #pragma unroll
            for (int j = 0; j < 4; ++j) {
                int byt = q * 128 + (((j * 16 + c) * 2) ^ sw);
                *reinterpret_cast<ushort*>(pbase + byt) = f2bf(s[j][r]);
            }
        }
        #pragma unroll
        for (int dblk = 0; dblk < 4; ++dblk)
            #pragma unroll
            for (int r = 0; r < 4; ++r)
                oacc[dblk][r] *= alpha[r];

        // PV: O[q][d] += P[q][key] * V^T[d][key]
        #pragma unroll
        for (int ks = 0; ks < 2; ++ks) {
            bf16x8 pf = *reinterpret_cast<const bf16x8*>(
                pbase + c * 128 + ((ks * 64 + g * 16) ^ ((c & 7) << 4)));
            #pragma unroll
            for (int dblk = 0; dblk < 4; ++dblk) {
                int d = dblk * 16 + c;
                bf16x8 vf = *reinterpret_cast<const bf16x8*>(
                    vbase + d * 128 + ((ks * 64 + g * 16) ^ ((d & 7) << 4)));
                oacc[dblk] = __builtin_amdgcn_mfma_f32_16x16x32_bf16(
                    pf, vf, oacc[dblk], 0, 0, 0);
            }
        }
        __syncthreads();   // drains prefetch vmcnt; all waves done with buf[cur]
    }

    // Epilogue: normalize, write bf16 (B,H,T,D).
    #pragma unroll
    for (int r = 0; r < 4; ++r) {
        float inv = 1.f / l_i[r];
        int q = q0 + w * 16 + g * 4 + r;
        #pragma unroll
        for (int dblk = 0; dblk < 4; ++dblk)
            og[((size_t)bh * SEQ + q) * HD + dblk * 16 + c] =
                f2bf(oacc[dblk][r] * inv);
    }
}

// ---------------------------------------------------------------------------
// Launch. ws (ushort units), 76 MB total:
//   tmp[NX]  (cast buf for q/k/v inputs, then V^T)
//   wqb|wkb|wvb|wob [4*NW] | tab (f32, 512KB)
//   qb[NX] | kb[NX] | vb[NX]  (vb reused as attn output)
// ---------------------------------------------------------------------------
extern "C" void kernel_launch(void* const* d_in, const int* in_sizes, int n_in,
                              void* d_out, int out_size, void* d_ws,
                              size_t ws_size, hipStream_t stream) {
    const float* query = (const float*)d_in[0];
    const float* key_  = (const float*)d_in[1];
    const float* value = (const float*)d_in[2];
    const float* wq    = (const float*)d_in[3];
    const float* bq    = (const float*)d_in[4];
    const float* wk    = (const float*)d_in[5];
    const float* bk    = (const float*)d_in[6];
    const float* wv    = (const float*)d_in[7];
    const float* bv    = (const float*)d_in[8];
    const float* wo    = (const float*)d_in[9];
    const float* bo    = (const float*)d_in[10];

    ushort* ws16 = (ushort*)d_ws;
    const size_t NX = (size_t)MROWS * EMB;   // 8388608 elements (16 MB bf16)
    const size_t NW = (size_t)EMB * EMB;     // 1048576 elements (2 MB bf16)
    ushort* tmp = ws16;
    ushort* wqb = ws16 + NX;
    ushort* wkb = wqb + NW;
    ushort* wvb = wkb + NW;
    ushort* wob = wvb + NW;
    float*  tab = (float*)(wob + NW);
    ushort* qb  = (ushort*)(tab + 4 * SEQ * HALF);
    ushort* kb  = qb + NX;
    ushort* vb  = kb + NX;

    const int nx4 = (int)(NX / 4), nw4 = (int)(NW / 4);

    cast_kernel<<<nw4 / 256, 256, 0, stream>>>(wq, wqb, nw4);
    cast_kernel<<<nw4 / 256, 256, 0, stream>>>(wk, wkb, nw4);
    cast_kernel<<<nw4 / 256, 256, 0, stream>>>(wv, wvb, nw4);
    cast_kernel<<<nw4 / 256, 256, 0, stream>>>(wo, wob, nw4);
    xpos_tables_kernel<<<SEQ * HALF / 256, 256, 0, stream>>>(tab);

    cast_kernel<<<nx4 / 256, 256, 0, stream>>>(query, tmp, nx4);
    gemm_bf16_kernel<1><<<512, 256, 0, stream>>>(tmp, wqb, bq, tab, qb);
    cast_kernel<<<nx4 / 256, 256, 0, stream>>>(key_, tmp, nx4);
    gemm_bf16_kernel<2><<<512, 256, 0, stream>>>(tmp, wkb, bk, tab, kb);
    cast_kernel<<<nx4 / 256, 256, 0, stream>>>(value, tmp, nx4);
    gemm_bf16_kernel<0><<<512, 256, 0, stream>>>(tmp, wvb, bv, tab, vb);

    vtrans_kernel<<<dim3(16, 128), 256, 0, stream>>>(vb, tmp);  // tmp := V^T

    attn_kernel<<<2048, 256, 0, stream>>>(qb, kb, tmp, vb);     // vb := attn out

    gemm_bf16_kernel<3><<<512, 256, 0, stream>>>(vb, wob, bo, nullptr, d_out);
}